// Round 8
// baseline (573.987 us; speedup 1.0000x reference)
//
#include <hip/hip_runtime.h>

#define SEQ 128
#define BATCH 512
#define IN_DIM 128
#define HID 128

typedef float vf2 __attribute__((ext_vector_type(2)));

#define LOG2E 1.4426950408889634f

__device__ __forceinline__ float rcp_fast(float x) { return __builtin_amdgcn_rcpf(x); }
__device__ __forceinline__ float exp2_fast(float x) { return __builtin_amdgcn_exp2f(x); }
__device__ __forceinline__ float tanh_fast(float x) {
  float e2 = exp2_fast(x * (2.0f * LOG2E));
  return 1.0f - 2.0f * rcp_fast(1.0f + e2);
}
// DPP quad_perm lane swaps (VALU pipe): xor1 = 0xB1, xor2 = 0x4E, half-mirror = 0x141
__device__ __forceinline__ float dpp_xor1(float x) {
  return __int_as_float(__builtin_amdgcn_mov_dpp(__float_as_int(x), 0xB1, 0xF, 0xF, true));
}
__device__ __forceinline__ float dpp_xor2(float x) {
  return __int_as_float(__builtin_amdgcn_mov_dpp(__float_as_int(x), 0x4E, 0xF, 0xF, true));
}
__device__ __forceinline__ float row8_allsum(float s) {
  s += dpp_xor1(s);
  s += dpp_xor2(s);
  s += __int_as_float(__builtin_amdgcn_mov_dpp(__float_as_int(s), 0x141, 0xF, 0xF, true));
  return s;
}

// Prepass: Qx[tb][w] = sum_{d<128} X[tb][d]*Wq[w][d] + bq[w] (x-part).
__global__ __launch_bounds__(256) void qx_prepass(
    const float* __restrict__ X, const float* __restrict__ Wq,
    const float* __restrict__ bq, float* __restrict__ Qx)
{
  const int lane = threadIdx.x & 63;
  const int wv   = threadIdx.x >> 6;
  const int tb   = blockIdx.x * 4 + wv;
  const int r = lane >> 3, c = lane & 7;
  const float4* xp = (const float4*)(X + (size_t)tb * IN_DIM + 16 * c);
  const float4* wp = (const float4*)(Wq + r * 256 + 16 * c);
  float4 x0 = xp[0], x1 = xp[1], x2 = xp[2], x3 = xp[3];
  float4 w0 = wp[0], w1 = wp[1], w2 = wp[2], w3 = wp[3];
  float s = x0.x*w0.x + x0.y*w0.y + x0.z*w0.z + x0.w*w0.w
          + x1.x*w1.x + x1.y*w1.y + x1.z*w1.z + x1.w*w1.w
          + x2.x*w2.x + x2.y*w2.y + x2.z*w2.z + x2.w*w2.w
          + x3.x*w3.x + x3.y*w3.y + x3.z*w3.z + x3.w*w3.w;
  s = row8_allsum(s);
  if (c == 0) Qx[(size_t)tb * 8 + r] = s + bq[r];
}

// TWO batch elements per wave (lane halves), 256 blocks x 64 threads.
// Per element (32 lanes, l = lane&31):
//   q_in: wire r = l>>2, h-dims 32c..32c+31 (c = l&3); quad reduce = 2 DPPs.
//   gates: gate g = (l>>3)&3, h-outputs 16p..16p+15 (p = l&7).
//   cell:  lane owns h = 4l..4l+3.
// TM recursion (validated R4) with per-lane gate constants; gate-GEMM weights
// pre-scaled by -amul*log2e so activation = rcp(1+exp2(acc)).
__global__ __launch_bounds__(64, 1) void qlstm_kernel(
    const float* __restrict__ Qx, const float* __restrict__ Wq,
    const float* __restrict__ pf, const float* __restrict__ pi_, const float* __restrict__ pg,
    const float* __restrict__ po, const float* __restrict__ Wf, const float* __restrict__ bf,
    const float* __restrict__ Wi, const float* __restrict__ bi, const float* __restrict__ Wg,
    const float* __restrict__ bg, const float* __restrict__ Wo, const float* __restrict__ bo,
    float* __restrict__ out)
{
  __shared__ __align__(16) float h_sh[2][132];  // pad 132: e-offset shifts banks
  __shared__ __align__(16) float gsh[2][532];   // [e][g*132 + h]
  __shared__ __align__(16) float qs[2][20];     // (c,s) x 8 wires per element

  const int lane = threadIdx.x;
  const int e = lane >> 5;
  const int l = lane & 31;
  const int r = l >> 2, c = l & 3;
  const int g = (l >> 3) & 3, p = l & 7;
  const int b = blockIdx.x * 2 + e;

  const float* gW = (g == 0) ? Wf : (g == 1) ? Wi : (g == 2) ? Wg : Wo;
  const float* gB = (g == 0) ? bf : (g == 1) ? bi : (g == 2) ? bg : bo;
  const float* gP = (g == 0) ? pf : (g == 1) ? pi_ : (g == 2) ? pg : po;

  const float ascale = (g == 2) ? -2.0f * LOG2E : -LOG2E;
  const float amul   = (g == 2) ? 2.0f : 1.0f;
  const float oadd   = (g == 2) ? -1.0f : 0.0f;

  // ---- one-time register preloads ----
  // Wq h-part for wire r, dims 32c..32c+31 (16 vf2)
  vf2 wh[16];
  {
    const vf2* whp = (const vf2*)(Wq + r * 256 + 128 + 32 * c);
#pragma unroll
    for (int k = 0; k < 16; ++k) wh[k] = whp[k];
  }
  // gate-GEMM weights (pre-scaled): gate g, h = 16p..16p+15
  vf2 wg2[8][8];
  vf2 bias2[8];
#pragma unroll
  for (int w = 0; w < 8; ++w)
#pragma unroll
    for (int j = 0; j < 8; ++j) {
      wg2[w][j].x = gW[(16 * p + 2 * j)     * 8 + w] * ascale;
      wg2[w][j].y = gW[(16 * p + 2 * j + 1) * 8 + w] * ascale;
    }
#pragma unroll
  for (int j = 0; j < 8; ++j) {
    bias2[j].x = gB[16 * p + 2 * j]     * ascale;
    bias2[j].y = gB[16 * p + 2 * j + 1] * ascale;
  }
  // TM constants for this lane's gate
  vf2 cbsb[8];
  float C1[8], S1[8];
#pragma unroll
  for (int w = 0; w < 8; ++w) {
    float th0 = gP[w], th1 = gP[8 + w];
    cbsb[w].x = cosf(th0); cbsb[w].y = sinf(th0);
    C1[w] = cosf(th1); S1[w] = sinf(th1);
  }

  // init state
  {
    float4 z4; z4.x = 0.0f; z4.y = 0.0f; z4.z = 0.0f; z4.w = 0.0f;
    *(float4*)(h_sh[e] + 4 * l) = z4;
  }
  float c4[4] = {0.0f, 0.0f, 0.0f, 0.0f};
  float4 hlast; hlast.x = 0.0f; hlast.y = 0.0f; hlast.z = 0.0f; hlast.w = 0.0f;

  // Qx prefetch (this lane's wire r)
  float nqx = Qx[(size_t)b * 8 + r];

#pragma unroll 1
  for (int t = 0; t < SEQ; ++t) {
    float qxv = nqx;
    if (t + 1 < SEQ) nqx = Qx[((size_t)(t + 1) * BATCH + b) * 8 + r];

    // ---- q_in: h read (bank-rotated), 16 pk_fma, 2-DPP quad reduce ----
    float4 hv[8];
    {
      const float4* hb = (const float4*)(h_sh[e] + 32 * c);
#pragma unroll
      for (int k = 0; k < 8; ++k) { int kk = (k + 2 * c) & 7; hv[kk] = hb[kk]; }
    }
    vf2 aq; aq.x = 0.0f; aq.y = 0.0f;
#pragma unroll
    for (int k = 0; k < 8; ++k) {
      vf2 a; a.x = hv[k].x; a.y = hv[k].y;
      vf2 bq2; bq2.x = hv[k].z; bq2.y = hv[k].w;
      aq += wh[2 * k] * a;
      aq += wh[2 * k + 1] * bq2;
    }
    float s = aq.x + aq.y;
    s += dpp_xor1(s);
    s += dpp_xor2(s);
    float z = s + qxv;
    float sz, cz;
    __sincosf(z, &sz, &cz);

    // ---- per-element broadcast of (c,s) x 8 wires via wave-private LDS ----
    if (c == 0) {
      float2 cs; cs.x = cz; cs.y = sz;
      *(float2*)(qs[e] + 2 * r) = cs;
    }
    float cq[8], sq[8];
    {
      const float4* q4 = (const float4*)(qs[e]);
      float4 q0 = q4[0], q1 = q4[1], q2 = q4[2], q3 = q4[3];
      cq[0] = q0.x; sq[0] = q0.y; cq[1] = q0.z; sq[1] = q0.w;
      cq[2] = q1.x; sq[2] = q1.y; cq[3] = q1.z; sq[3] = q1.w;
      cq[4] = q2.x; sq[4] = q2.y; cq[5] = q2.z; sq[5] = q2.w;
      cq[6] = q3.x; sq[6] = q3.y; cq[7] = q3.z; sq[7] = q3.w;
    }

    // ---- TM chain (per-lane gate constants) + fused gate GEMM ----
    vf2 acc[8];
#pragma unroll
    for (int j = 0; j < 8; ++j) acc[j] = bias2[j];
    float u, d, P, R;
    {
      vf2 KA0 = cbsb[0] * cq[0];
      u = C1[0];
      d = C1[0] * KA0.x;
      P = -S1[0] * KA0.y;
      R = -S1[0] * sq[0];
    }
#pragma unroll
    for (int w = 1; w < 8; ++w) {
      vf2 KA = cbsb[w] * cq[w];
      float K = KA.x, A2 = KA.y, B2 = sq[w];
      float Md = fmaf(A2, P, d);            // == ev[w-1]
      float MP = fmaf(A2, d, P);
      float Mu = fmaf(K, u, -(B2 * R));
      float MR = fmaf(B2, u, K * R);
#pragma unroll
      for (int j = 0; j < 8; ++j) acc[j] += Md * wg2[w - 1][j];
      vf2 ud2; ud2.x = Md; ud2.y = Mu;
      vf2 PR2; PR2.x = MP; PR2.y = MR;
      ud2 = C1[w] * ud2;
      PR2 = -S1[w] * PR2;
      u = ud2.x; d = ud2.y; P = PR2.x; R = PR2.y;
    }
    float ev7 = d + P;
#pragma unroll
    for (int j = 0; j < 8; ++j) acc[j] += ev7 * wg2[7][j];

    // ---- activation: sg = rcp(1+exp2(acc)); out = amul*sg + oadd ----
    float4 o4[4];
#pragma unroll
    for (int j = 0; j < 8; ++j) {
      float s0 = rcp_fast(1.0f + exp2_fast(acc[j].x));
      float s1 = rcp_fast(1.0f + exp2_fast(acc[j].y));
      vf2 ov; ov.x = fmaf(amul, s0, oadd); ov.y = fmaf(amul, s1, oadd);
      ((vf2*)o4)[j] = ov;
    }
    {
      float* gw = gsh[e] + 132 * g + 16 * p;
#pragma unroll
      for (int k = 0; k < 4; ++k) {
        int kk = (k + g + p) & 3;
        *(float4*)(gw + 4 * kk) = o4[kk];
      }
    }

    // ---- cell update: lane owns h = 4l..4l+3 ----
    float4 gv[4];
#pragma unroll
    for (int j = 0; j < 4; ++j) {
      int jj = (j + l) & 3;
      gv[jj] = *(const float4*)(gsh[e] + 132 * jj + 4 * l);
    }
    float4 hn;
    c4[0] = fmaf(gv[0].x, c4[0], gv[1].x * gv[2].x);
    c4[1] = fmaf(gv[0].y, c4[1], gv[1].y * gv[2].y);
    c4[2] = fmaf(gv[0].z, c4[2], gv[1].z * gv[2].z);
    c4[3] = fmaf(gv[0].w, c4[3], gv[1].w * gv[2].w);
    hn.x = gv[3].x * tanh_fast(c4[0]);
    hn.y = gv[3].y * tanh_fast(c4[1]);
    hn.z = gv[3].z * tanh_fast(c4[2]);
    hn.w = gv[3].w * tanh_fast(c4[3]);
    *(float4*)(h_sh[e] + 4 * l) = hn;
    hlast = hn;

    *(float4*)(out + ((size_t)t * BATCH + b) * HID + 4 * l) = hn;
  }

  // hx, cx
  {
    size_t base = (size_t)SEQ * BATCH * HID;
    *(float4*)(out + base + (size_t)b * HID + 4 * l) = hlast;
    float4 cv; cv.x = c4[0]; cv.y = c4[1]; cv.z = c4[2]; cv.w = c4[3];
    *(float4*)(out + base + (size_t)BATCH * HID + (size_t)b * HID + 4 * l) = cv;
  }
}

extern "C" void kernel_launch(void* const* d_in, const int* in_sizes, int n_in,
                              void* d_out, int out_size, void* d_ws, size_t ws_size,
                              hipStream_t stream) {
  (void)in_sizes; (void)n_in; (void)out_size; (void)ws_size;
  const float* X   = (const float*)d_in[0];
  const float* Wq  = (const float*)d_in[1];
  const float* bq  = (const float*)d_in[2];
  const float* pf  = (const float*)d_in[3];
  const float* pi_ = (const float*)d_in[4];
  const float* pg  = (const float*)d_in[5];
  const float* po  = (const float*)d_in[6];
  const float* Wf  = (const float*)d_in[7];
  const float* bf  = (const float*)d_in[8];
  const float* Wi  = (const float*)d_in[9];
  const float* bi  = (const float*)d_in[10];
  const float* Wg  = (const float*)d_in[11];
  const float* bg  = (const float*)d_in[12];
  const float* Wo  = (const float*)d_in[13];
  const float* bo  = (const float*)d_in[14];
  float* out = (float*)d_out;
  float* Qx  = (float*)d_ws;                 // SEQ*BATCH*8 floats = 2 MB

  qx_prepass<<<(SEQ * BATCH) / 4, 256, 0, stream>>>(X, Wq, bq, Qx);
  qlstm_kernel<<<BATCH / 2, 64, 0, stream>>>(Qx, Wq, pf, pi_, pg, po,
                                             Wf, bf, Wi, bi, Wg, bg, Wo, bo, out);
}